// Round 11
// baseline (525.139 us; speedup 1.0000x reference)
//
#include <hip/hip_runtime.h>
#include <hip/hip_bf16.h>

// Problem constants (B,S,E,H,D) = (4,2048,1024,16,64)
#define PB 4
#define PS 2048
#define PE 1024
#define PH 16
#define PD 64

typedef __attribute__((ext_vector_type(8))) short bf16x8;
typedef __attribute__((ext_vector_type(4))) float f32x4;
typedef const __attribute__((address_space(1))) unsigned int* gas_t;
typedef __attribute__((address_space(3))) unsigned int* las_t;

__device__ __forceinline__ unsigned short f2bf(float f) {
  union { float f; unsigned int u; } v;
  v.f = f;
  unsigned int u = v.u;
  u += 0x7fffu + ((u >> 16) & 1u);  // RNE
  return (unsigned short)(u >> 16);
}

__device__ __forceinline__ f32x4 mfma16(bf16x8 a, bf16x8 b, f32x4 c) {
  return __builtin_amdgcn_mfma_f32_16x16x32_bf16(a, b, c, 0, 0, 0);
}

// ---------------- fp32 -> bf16 conversion (x, Wk, Wq, Wo fused) --------------
#define CVT_GROUPS ((PB * PS * PE + 3 * PE * PE) / 4)
#define CVT_BLOCKS (CVT_GROUPS / 256)   // 11264
__global__ __launch_bounds__(256) void cvt_kernel(
    const float* __restrict__ x, const float* __restrict__ wk,
    const float* __restrict__ wq, const float* __restrict__ wo,
    unsigned short* __restrict__ xb, unsigned short* __restrict__ wkb,
    unsigned short* __restrict__ wqb, unsigned short* __restrict__ wob) {
  const long long NX = (long long)PB * PS * PE;   // 8388608
  const long long NW = (long long)PE * PE;        // 1048576
  long long i = ((long long)blockIdx.x * 256 + threadIdx.x) * 4;
  const float* src;
  unsigned short* dst;
  long long off;
  if (i < NX)               { src = x;  dst = xb;  off = i; }
  else if (i < NX + NW)     { src = wk; dst = wkb; off = i - NX; }
  else if (i < NX + 2 * NW) { src = wq; dst = wqb; off = i - NX - NW; }
  else                      { src = wo; dst = wob; off = i - NX - 2 * NW; }
  float4 v = *(const float4*)(src + off);
  ushort4 o;
  o.x = f2bf(v.x); o.y = f2bf(v.y); o.z = f2bf(v.z); o.w = f2bf(v.w);
  *(ushort4*)(dst + off) = o;
}

// ---------------- Q / K NT GEMM, split by blockIdx.z -----------------------
// R5 structure + XCD panel swizzle. R10 counters (R4: VGPR_Count=140) show
// the allocator capped residency at 3 waves/SIMD = 3 blocks/CU despite the
// grid providing 4 -> __launch_bounds__(256,4) forces <=128 VGPR so all 4
// blocks co-reside. Panel map interleaves z: Q(ny) and K(ny) are adjacent
// panels on the SAME XCD, so each A m-panel is fetched from HBM once.
__global__ __launch_bounds__(256, 4) void gemm_qknt(
    const unsigned short* __restrict__ A, const unsigned short* __restrict__ Bq,
    const unsigned short* __restrict__ Bk,
    unsigned short* __restrict__ QT, unsigned short* __restrict__ Kb) {
  const int K = PE, N = PE;
  __shared__ __attribute__((aligned(16))) unsigned short As[128 * 64];
  __shared__ __attribute__((aligned(16))) unsigned short Bs[128 * 64];
  const int tid = threadIdx.x;
  const int wave = tid >> 6, lane = tid & 63;
  const int quad = lane >> 4, ln = lane & 15;

  // XCD swizzle (assumes XCD = flat_id % 8): 16 panels per XCD; each panel
  // pair (p even/odd) = (Q, K) of the same m-row. Bijective over 1024.
  const int fp = (int)blockIdx.x + ((int)blockIdx.y << 3) + ((int)blockIdx.z << 9);
  const int xr = fp & 7, sl = fp >> 3;
  const int nx = sl & 7;                    // n-tile 0..7
  const int p  = xr * 16 + (sl >> 3);       // panel 0..127
  const int isK = p & 1, ny = p >> 1;       // z interleaved: A fetched once
  const int m0 = ny * 128, n0 = nx * 128;
  const int wm = (wave >> 1) * 64, wn = (wave & 1) * 64;
  const unsigned short* __restrict__ Bsrc = isK ? Bk : Bq;

  f32x4 acc[4][4];
#pragma unroll
  for (int i = 0; i < 4; ++i)
#pragma unroll
    for (int j = 0; j < 4; ++j)
#pragma unroll
      for (int r = 0; r < 4; ++r) acc[i][j][r] = 0.f;

  for (int k0 = 0; k0 < K; k0 += 64) {
#pragma unroll
    for (int it = 0; it < 4; ++it) {
      const int idx = it * 256 + tid;
      const int row = idx >> 3, ch = idx & 7;
      const int gch = ch ^ (row & 7);
      __builtin_amdgcn_global_load_lds(
          (gas_t)(const void*)(A + (size_t)(m0 + row) * K + k0 + gch * 8),
          (las_t)(void*)((char*)As + idx * 16), 16, 0, 0);
      __builtin_amdgcn_global_load_lds(
          (gas_t)(const void*)(Bsrc + (size_t)(n0 + row) * K + k0 + gch * 8),
          (las_t)(void*)((char*)Bs + idx * 16), 16, 0, 0);
    }
    __syncthreads();
#pragma unroll
    for (int kc = 0; kc < 2; ++kc) {
      bf16x8 af[4], bfr[4];
#pragma unroll
      for (int t = 0; t < 4; ++t) {
        const int ra = wm + t * 16 + ln;
        const int rb = wn + t * 16 + ln;
        af[t]  = *(const bf16x8*)(As + ra * 64 + ((kc * 4 + quad) ^ (ra & 7)) * 8);
        bfr[t] = *(const bf16x8*)(Bs + rb * 64 + ((kc * 4 + quad) ^ (rb & 7)) * 8);
      }
      if (!isK) {
#pragma unroll
        for (int mt = 0; mt < 4; ++mt)
#pragma unroll
          for (int nt = 0; nt < 4; ++nt)
            acc[mt][nt] = mfma16(af[mt], bfr[nt], acc[mt][nt]);
      } else {
#pragma unroll
        for (int mt = 0; mt < 4; ++mt)
#pragma unroll
          for (int nt = 0; nt < 4; ++nt)
            acc[mt][nt] = mfma16(bfr[nt], af[mt], acc[mt][nt]);  // swapped
      }
    }
    __syncthreads();
  }

  const float CEXP = 0.045084220f;  // log2(e)/32 folded into K
  if (!isK) {
    // Q: D[token=quad*4+r][feat=ln] -> transposed per-head ushort4 store
#pragma unroll
    for (int mt = 0; mt < 4; ++mt)
#pragma unroll
      for (int nt = 0; nt < 4; ++nt) {
        const int row = m0 + wm + mt * 16 + quad * 4;  // token (+r)
        const int col = n0 + wn + nt * 16 + ln;        // feature
        const int b = row >> 11, s = row & 2047;
        const int h = col >> 6, d = col & 63;
        ushort4 ov;
        ov.x = f2bf(acc[mt][nt][0]); ov.y = f2bf(acc[mt][nt][1]);
        ov.z = f2bf(acc[mt][nt][2]); ov.w = f2bf(acc[mt][nt][3]);
        *(ushort4*)(QT + (((size_t)(b * PH + h) * PD + d) * PS + s)) = ov;
      }
  } else {
    // K: D[feat=quad*4+r][token=ln] -> row-major ushort4 store, pre-scaled
#pragma unroll
    for (int mt = 0; mt < 4; ++mt)
#pragma unroll
      for (int nt = 0; nt < 4; ++nt) {
        const int krow = m0 + wm + mt * 16 + ln;        // token
        const int kcol = n0 + wn + nt * 16 + quad * 4;  // feature base
        ushort4 kv;
        kv.x = f2bf(acc[mt][nt][0] * CEXP); kv.y = f2bf(acc[mt][nt][1] * CEXP);
        kv.z = f2bf(acc[mt][nt][2] * CEXP); kv.w = f2bf(acc[mt][nt][3] * CEXP);
        *(ushort4*)(Kb + (size_t)krow * N + kcol) = kv;
      }
  }
}

// ---------------- out-projection NT GEMM: C = A * Wo^T + bo (fp32) ----------
// R5 structure (64x128 tiles) + XCD panel swizzle + forced 4 blocks/CU.
__global__ __launch_bounds__(256, 4) void gemm_out(
    const unsigned short* __restrict__ A, const unsigned short* __restrict__ Bm,
    const float* __restrict__ bias, float* __restrict__ Cf) {
  const int K = PE, N = PE;
  __shared__ __attribute__((aligned(16))) unsigned short As[64 * 64];
  __shared__ __attribute__((aligned(16))) unsigned short Bs[128 * 64];
  const int tid = threadIdx.x;
  const int wave = tid >> 6, lane = tid & 63;
  const int quad = lane >> 4, ln = lane & 15;

  const int fp = (int)blockIdx.x + ((int)blockIdx.y << 3);
  const int xr = fp & 7, sl = fp >> 3;
  const int nx = sl & 7;                    // n-tile 0..7
  const int ny = xr * 16 + (sl >> 3);       // m-panel 0..127
  const int m0 = ny * 64, n0 = nx * 128;
  const int wm = (wave >> 1) * 32, wn = (wave & 1) * 64;

  f32x4 acc[2][4];
#pragma unroll
  for (int i = 0; i < 2; ++i)
#pragma unroll
    for (int j = 0; j < 4; ++j)
#pragma unroll
      for (int r = 0; r < 4; ++r) acc[i][j][r] = 0.f;

  for (int k0 = 0; k0 < K; k0 += 64) {
#pragma unroll
    for (int it = 0; it < 2; ++it) {
      const int idx = it * 256 + tid;
      const int row = idx >> 3, ch = idx & 7;
      const int gch = ch ^ (row & 7);
      __builtin_amdgcn_global_load_lds(
          (gas_t)(const void*)(A + (size_t)(m0 + row) * K + k0 + gch * 8),
          (las_t)(void*)((char*)As + idx * 16), 16, 0, 0);
    }
#pragma unroll
    for (int it = 0; it < 4; ++it) {
      const int idx = it * 256 + tid;
      const int row = idx >> 3, ch = idx & 7;
      const int gch = ch ^ (row & 7);
      __builtin_amdgcn_global_load_lds(
          (gas_t)(const void*)(Bm + (size_t)(n0 + row) * K + k0 + gch * 8),
          (las_t)(void*)((char*)Bs + idx * 16), 16, 0, 0);
    }
    __syncthreads();
#pragma unroll
    for (int kc = 0; kc < 2; ++kc) {
      bf16x8 af[2], bfr[4];
#pragma unroll
      for (int t = 0; t < 2; ++t) {
        const int ra = wm + t * 16 + ln;
        af[t] = *(const bf16x8*)(As + ra * 64 + ((kc * 4 + quad) ^ (ra & 7)) * 8);
      }
#pragma unroll
      for (int t = 0; t < 4; ++t) {
        const int rb = wn + t * 16 + ln;
        bfr[t] = *(const bf16x8*)(Bs + rb * 64 + ((kc * 4 + quad) ^ (rb & 7)) * 8);
      }
#pragma unroll
      for (int mt = 0; mt < 2; ++mt)
#pragma unroll
        for (int nt = 0; nt < 4; ++nt)
          acc[mt][nt] = mfma16(bfr[nt], af[mt], acc[mt][nt]);  // swapped
    }
    __syncthreads();
  }

#pragma unroll
  for (int mt = 0; mt < 2; ++mt) {
#pragma unroll
    for (int nt = 0; nt < 4; ++nt) {
      const int row  = m0 + wm + mt * 16 + ln;        // token
      const int colb = n0 + wn + nt * 16 + quad * 4;  // feature base
      const float4 bv = *(const float4*)(bias + colb);
      float4 ov;
      ov.x = acc[mt][nt][0] + bv.x; ov.y = acc[mt][nt][1] + bv.y;
      ov.z = acc[mt][nt][2] + bv.z; ov.w = acc[mt][nt][3] + bv.w;
      *(float4*)(Cf + (size_t)row * N + colb) = ov;
    }
  }
}

// ---------------- fused causal attention, V == Q (reference bug) -------------
// v9 (proven 76.2us): v5 body + XCD flat swizzle (FETCH 193MB -> 21MB).
// MfmaUtil 19% = exact MFMA floor; VALUBusy 54% is the dominant pipe.
// Structural variants v3/v4 (pipelining), v6/v7 (32x32), v8 (128-thread)
// all lost — frozen.
__global__ __launch_bounds__(256) void attn_kernel(
    const unsigned short* __restrict__ QT,  // [b,h][d=64][s=2048]
    const unsigned short* __restrict__ Kb,  // [b*s][E] row-major, pre-scaled
    unsigned short* __restrict__ Ab) {      // [b*s][E] row-major
  __shared__ __attribute__((aligned(16))) unsigned short Ks[64 * 64];
  __shared__ __attribute__((aligned(16))) unsigned short Vs[64 * 64];
  __shared__ __attribute__((aligned(16))) unsigned short Ps[4][16 * 72];

  const int tid = threadIdx.x;
  const int wave = tid >> 6, lane = tid & 63;
  const int quad = lane >> 4, ln = lane & 15;

  // XCD swizzle (assumes XCD = flat_id % 8): 16 q-chunk blocks of one (b,h)
  // contiguous on one XCD. Bijective over 1024 blocks.
  const int fp = (int)blockIdx.x + ((int)blockIdx.y << 4) + ((int)blockIdx.z << 8);
  const int xr = fp & 7, sl = fp >> 3;
  const int bx = sl & 15;                 // q-pair index 0..15
  const int g  = xr * 8 + (sl >> 4);      // (b,h) group 0..63
  const int h = g & 15, b = g >> 4;

  const size_t hoff  = ((size_t)b * PS) * PE + (size_t)h * PD;
  const size_t hofft = ((size_t)(b * PH + h) * PD) * PS;
  const int srow = tid >> 3, sch = tid & 7;

  for (int pass = 0; pass < 2; ++pass) {
    const int qc = pass ? bx : 31 - bx;
    const int qw0 = qc * 64 + wave * 16;

    // Q fragment: 16 q-rows x 64 d, B-operand layout (lane ln = q-row qw0+ln)
    bf16x8 qfr[2];
#pragma unroll
    for (int c = 0; c < 2; ++c) {
      union { unsigned short u[8]; bf16x8 v; } tmp;
#pragma unroll
      for (int j = 0; j < 8; ++j)
        tmp.u[j] = QT[hofft + (size_t)(c * 32 + quad * 8 + j) * PS + qw0 + ln];
      qfr[c] = tmp.v;
    }

    f32x4 o[4];
    float psum = 0.f;
#pragma unroll
    for (int td = 0; td < 4; ++td)
#pragma unroll
      for (int r = 0; r < 4; ++r) o[td][r] = 0.f;

    const int ktend = qc + 1;
    for (int kt = 0; kt < ktend; ++kt) {
      const int k0 = kt * 64;

#pragma unroll
      for (int r = 0; r < 2; ++r) {
        const int row = r * 32 + srow;
        const int gch = sch ^ (row & 7);
        __builtin_amdgcn_global_load_lds(
            (gas_t)(const void*)(Kb + hoff + (size_t)(k0 + row) * PE + gch * 8),
            (las_t)(void*)((char*)Ks + (r * 256 + tid) * 16), 16, 0, 0);
        __builtin_amdgcn_global_load_lds(
            (gas_t)(const void*)(QT + hofft + (size_t)row * PS + k0 + gch * 8),
            (las_t)(void*)((char*)Vs + (r * 256 + tid) * 16), 16, 0, 0);
      }
      __syncthreads();

      // QK^T: sacc[mk] covers k-rows (mk*16 + quad*4 + r), q-col = ln
      f32x4 sacc[4];
#pragma unroll
      for (int mk = 0; mk < 4; ++mk)
#pragma unroll
        for (int r = 0; r < 4; ++r) sacc[mk][r] = 0.f;
      __builtin_amdgcn_s_setprio(1);
#pragma unroll
      for (int c = 0; c < 2; ++c) {
        const int ch = ((c * 4 + quad) ^ (ln & 7)) * 8;
        bf16x8 kf[4];
#pragma unroll
        for (int mk = 0; mk < 4; ++mk)
          kf[mk] = *(const bf16x8*)(Ks + (mk * 16 + ln) * 64 + ch);
#pragma unroll
        for (int mk = 0; mk < 4; ++mk)
          sacc[mk] = mfma16(kf[mk], qfr[c], sacc[mk]);
      }
      __builtin_amdgcn_s_setprio(0);

      const bool edge = (k0 + 63) > qw0;
#pragma unroll
      for (int mk = 0; mk < 4; ++mk) {
        float p[4];
#pragma unroll
        for (int r = 0; r < 4; ++r)
          p[r] = __builtin_amdgcn_exp2f(sacc[mk][r]);
        if (edge) {
          const int qg = qw0 + ln;
#pragma unroll
          for (int r = 0; r < 4; ++r) {
            const int kg = k0 + mk * 16 + quad * 4 + r;
            p[r] = (kg <= qg) ? p[r] : 0.f;
          }
        }
        psum += (p[0] + p[1]) + (p[2] + p[3]);
        union { __hip_bfloat162 h2; unsigned int u; } u01, u23;
        u01.h2 = __float22bfloat162_rn(float2{p[0], p[1]});
        u23.h2 = __float22bfloat162_rn(float2{p[2], p[3]});
        *(uint2*)(&Ps[wave][ln * 72 + mk * 16 + quad * 4]) =
            uint2{u01.u, u23.u};
      }

      // PV: o[td] covers d-cols td*16+ln, q-rows quad*4+r
      __builtin_amdgcn_s_setprio(1);
#pragma unroll
      for (int c = 0; c < 2; ++c) {
        const int ch = ((c * 4 + quad) ^ (ln & 7)) * 8;
        bf16x8 pf = *(const bf16x8*)(&Ps[wave][ln * 72 + c * 32 + quad * 8]);
#pragma unroll
        for (int td = 0; td < 4; ++td) {
          bf16x8 vfd = *(const bf16x8*)(Vs + (td * 16 + ln) * 64 + ch);
          o[td] = mfma16(pf, vfd, o[td]);
        }
      }
      __builtin_amdgcn_s_setprio(0);
      __syncthreads();
    }

    psum += __shfl_xor(psum, 16, 64);
    psum += __shfl_xor(psum, 32, 64);
    float invq[4];
#pragma unroll
    for (int r = 0; r < 4; ++r)
      invq[r] = 1.f / __shfl(psum, quad * 4 + r, 64);

#pragma unroll
    for (int r = 0; r < 4; ++r) {
      const int qg = qw0 + quad * 4 + r;
#pragma unroll
      for (int td = 0; td < 4; ++td)
        Ab[hoff + (size_t)qg * PE + td * 16 + ln] =
            f2bf(o[td][r] * invq[r]);
    }
  }
}

// ---------------------------------------------------------------------------
extern "C" void kernel_launch(void* const* d_in, const int* in_sizes, int n_in,
                              void* d_out, int out_size, void* d_ws, size_t ws_size,
                              hipStream_t stream) {
  (void)in_sizes; (void)n_in; (void)out_size; (void)ws_size;
  const float* x  = (const float*)d_in[0];
  const float* Wk = (const float*)d_in[1];
  const float* Wq = (const float*)d_in[2];
  // d_in[3] = Wv : dead in the reference (V = Q bug) — never touched.
  const float* Wo = (const float*)d_in[4];
  const float* bo = (const float*)d_in[5];
  float* out = (float*)d_out;

  char* ws = (char*)d_ws;
  unsigned short* xb  = (unsigned short*)(ws);                       // 16 MiB
  unsigned short* wkb = (unsigned short*)(ws + (16u << 20));         //  2 MiB
  unsigned short* wqb = (unsigned short*)(ws + (18u << 20));         //  2 MiB
  unsigned short* wob = (unsigned short*)(ws + (20u << 20));         //  2 MiB
  unsigned short* QT  = (unsigned short*)(ws + (22u << 20));         // 16 MiB
  unsigned short* Kb  = (unsigned short*)(ws + (38u << 20));         // 16 MiB
  unsigned short* Ab  = xb;  // alias: xb dead after gemm_qknt

  const int M = PB * PS;  // 8192

  // 1) fp32 -> bf16
  cvt_kernel<<<dim3(CVT_BLOCKS), dim3(256), 0, stream>>>(
      x, Wk, Wq, Wo, xb, wkb, wqb, wob);

  // 2) Q = x Wq^T (-> QT transposed), K = x Wk^T (-> row-major, scaled).
  //    1024 blocks, forced 4 blocks/CU, z-interleaved XCD panels.
  gemm_qknt<<<dim3(PE / 128, M / 128, 2), dim3(256), 0, stream>>>(
      xb, wqb, wkb, QT, Kb);

  // 3) causal attention (V = Q) — v9 frozen (76us)
  attn_kernel<<<dim3(16, PH, PB), dim3(256), 0, stream>>>(QT, Kb, Ab);

  // 4) out = attn Wo^T + bo (fp32) — 64x128 tiles, forced 4 blocks/CU
  gemm_out<<<dim3(PE / 128, M / 64), dim3(256), 0, stream>>>(
      Ab, wob, bo, out);
}

// Round 12
// 240.838 us; speedup vs baseline: 2.1805x; 2.1805x over previous
//
#include <hip/hip_runtime.h>
#include <hip/hip_bf16.h>

// Problem constants (B,S,E,H,D) = (4,2048,1024,16,64)
#define PB 4
#define PS 2048
#define PE 1024
#define PH 16
#define PD 64

typedef __attribute__((ext_vector_type(8))) short bf16x8;
typedef __attribute__((ext_vector_type(4))) float f32x4;
typedef const __attribute__((address_space(1))) unsigned int* gas_t;
typedef __attribute__((address_space(3))) unsigned int* las_t;

__device__ __forceinline__ unsigned short f2bf(float f) {
  union { float f; unsigned int u; } v;
  v.f = f;
  unsigned int u = v.u;
  u += 0x7fffu + ((u >> 16) & 1u);  // RNE
  return (unsigned short)(u >> 16);
}

__device__ __forceinline__ f32x4 mfma16(bf16x8 a, bf16x8 b, f32x4 c) {
  return __builtin_amdgcn_mfma_f32_16x16x32_bf16(a, b, c, 0, 0, 0);
}

// ---------------- fp32 -> bf16 conversion (x, Wk, Wq, Wo fused) --------------
#define CVT_GROUPS ((PB * PS * PE + 3 * PE * PE) / 4)
#define CVT_BLOCKS (CVT_GROUPS / 256)   // 11264
__global__ __launch_bounds__(256) void cvt_kernel(
    const float* __restrict__ x, const float* __restrict__ wk,
    const float* __restrict__ wq, const float* __restrict__ wo,
    unsigned short* __restrict__ xb, unsigned short* __restrict__ wkb,
    unsigned short* __restrict__ wqb, unsigned short* __restrict__ wob) {
  const long long NX = (long long)PB * PS * PE;   // 8388608
  const long long NW = (long long)PE * PE;        // 1048576
  long long i = ((long long)blockIdx.x * 256 + threadIdx.x) * 4;
  const float* src;
  unsigned short* dst;
  long long off;
  if (i < NX)               { src = x;  dst = xb;  off = i; }
  else if (i < NX + NW)     { src = wk; dst = wkb; off = i - NX; }
  else if (i < NX + 2 * NW) { src = wq; dst = wqb; off = i - NX - NW; }
  else                      { src = wo; dst = wob; off = i - NX - 2 * NW; }
  float4 v = *(const float4*)(src + off);
  ushort4 o;
  o.x = f2bf(v.x); o.y = f2bf(v.y); o.z = f2bf(v.z); o.w = f2bf(v.w);
  *(ushort4*)(dst + off) = o;
}

// ---------------- Q / K NT GEMM, 64x128 tiles, split by panel parity --------
// R11 lesson: __launch_bounds__(256,4) on the 128x128 version spilled the
// 64-reg accumulator to scratch (VGPR_Count 64, WRITE_SIZE 756MB, 340us).
// Fix is STRUCTURAL: 64x128 tile -> acc[2][4] (32 regs), natural VGPR ~96,
// 4 waves/SIMD without forcing. 2048 blocks; z-interleaved XCD panel map
// (Q/K of one m-panel adjacent on the same XCD -> A fetched once).
__global__ __launch_bounds__(256) void gemm_qknt(
    const unsigned short* __restrict__ A, const unsigned short* __restrict__ Bq,
    const unsigned short* __restrict__ Bk,
    unsigned short* __restrict__ QT, unsigned short* __restrict__ Kb) {
  const int K = PE, N = PE;
  __shared__ __attribute__((aligned(16))) unsigned short As[64 * 64];
  __shared__ __attribute__((aligned(16))) unsigned short Bs[128 * 64];
  const int tid = threadIdx.x;
  const int wave = tid >> 6, lane = tid & 63;
  const int quad = lane >> 4, ln = lane & 15;

  // XCD swizzle (assumes XCD = flat_id % 8): 32 panel-units per XCD;
  // consecutive units (even,odd) = (Q,K) of the same 64-row m-panel.
  // Bijective over 2048 blocks.
  const int fp = (int)blockIdx.x + ((int)blockIdx.y << 3) + ((int)blockIdx.z << 10);
  const int xr = fp & 7, sl = fp >> 3;         // sl 0..255
  const int nx = sl & 7;                       // n-tile 0..7
  const int pp = xr * 32 + (sl >> 3);          // panel-unit 0..255
  const int isK = pp & 1, ny = pp >> 1;        // m-panel 0..127
  const int m0 = ny * 64, n0 = nx * 128;
  const int wm = (wave >> 1) * 32, wn = (wave & 1) * 64;
  const unsigned short* __restrict__ Bsrc = isK ? Bk : Bq;

  f32x4 acc[2][4];
#pragma unroll
  for (int i = 0; i < 2; ++i)
#pragma unroll
    for (int j = 0; j < 4; ++j)
#pragma unroll
      for (int r = 0; r < 4; ++r) acc[i][j][r] = 0.f;

  for (int k0 = 0; k0 < K; k0 += 64) {
#pragma unroll
    for (int it = 0; it < 2; ++it) {
      const int idx = it * 256 + tid;
      const int row = idx >> 3, ch = idx & 7;
      const int gch = ch ^ (row & 7);
      __builtin_amdgcn_global_load_lds(
          (gas_t)(const void*)(A + (size_t)(m0 + row) * K + k0 + gch * 8),
          (las_t)(void*)((char*)As + idx * 16), 16, 0, 0);
    }
#pragma unroll
    for (int it = 0; it < 4; ++it) {
      const int idx = it * 256 + tid;
      const int row = idx >> 3, ch = idx & 7;
      const int gch = ch ^ (row & 7);
      __builtin_amdgcn_global_load_lds(
          (gas_t)(const void*)(Bsrc + (size_t)(n0 + row) * K + k0 + gch * 8),
          (las_t)(void*)((char*)Bs + idx * 16), 16, 0, 0);
    }
    __syncthreads();
#pragma unroll
    for (int kc = 0; kc < 2; ++kc) {
      bf16x8 af[2], bfr[4];
#pragma unroll
      for (int t = 0; t < 2; ++t) {
        const int ra = wm + t * 16 + ln;
        af[t] = *(const bf16x8*)(As + ra * 64 + ((kc * 4 + quad) ^ (ra & 7)) * 8);
      }
#pragma unroll
      for (int t = 0; t < 4; ++t) {
        const int rb = wn + t * 16 + ln;
        bfr[t] = *(const bf16x8*)(Bs + rb * 64 + ((kc * 4 + quad) ^ (rb & 7)) * 8);
      }
      if (!isK) {
#pragma unroll
        for (int mt = 0; mt < 2; ++mt)
#pragma unroll
          for (int nt = 0; nt < 4; ++nt)
            acc[mt][nt] = mfma16(af[mt], bfr[nt], acc[mt][nt]);
      } else {
#pragma unroll
        for (int mt = 0; mt < 2; ++mt)
#pragma unroll
          for (int nt = 0; nt < 4; ++nt)
            acc[mt][nt] = mfma16(bfr[nt], af[mt], acc[mt][nt]);  // swapped
      }
    }
    __syncthreads();
  }

  const float CEXP = 0.045084220f;  // log2(e)/32 folded into K
  if (!isK) {
    // Q: D[token=quad*4+r][feat=ln] -> transposed per-head ushort4 store
#pragma unroll
    for (int mt = 0; mt < 2; ++mt)
#pragma unroll
      for (int nt = 0; nt < 4; ++nt) {
        const int row = m0 + wm + mt * 16 + quad * 4;  // token (+r)
        const int col = n0 + wn + nt * 16 + ln;        // feature
        const int b = row >> 11, s = row & 2047;
        const int h = col >> 6, d = col & 63;
        ushort4 ov;
        ov.x = f2bf(acc[mt][nt][0]); ov.y = f2bf(acc[mt][nt][1]);
        ov.z = f2bf(acc[mt][nt][2]); ov.w = f2bf(acc[mt][nt][3]);
        *(ushort4*)(QT + (((size_t)(b * PH + h) * PD + d) * PS + s)) = ov;
      }
  } else {
    // K: D[feat=quad*4+r][token=ln] -> row-major ushort4 store, pre-scaled
#pragma unroll
    for (int mt = 0; mt < 2; ++mt)
#pragma unroll
      for (int nt = 0; nt < 4; ++nt) {
        const int krow = m0 + wm + mt * 16 + ln;        // token
        const int kcol = n0 + wn + nt * 16 + quad * 4;  // feature base
        ushort4 kv;
        kv.x = f2bf(acc[mt][nt][0] * CEXP); kv.y = f2bf(acc[mt][nt][1] * CEXP);
        kv.z = f2bf(acc[mt][nt][2] * CEXP); kv.w = f2bf(acc[mt][nt][3] * CEXP);
        *(ushort4*)(Kb + (size_t)krow * N + kcol) = kv;
      }
  }
}

// ---------------- out-projection NT GEMM: C = A * Wo^T + bo (fp32) ----------
// R10 version (no launch_bounds force): 64x128 tiles + XCD panel swizzle.
__global__ __launch_bounds__(256) void gemm_out(
    const unsigned short* __restrict__ A, const unsigned short* __restrict__ Bm,
    const float* __restrict__ bias, float* __restrict__ Cf) {
  const int K = PE, N = PE;
  __shared__ __attribute__((aligned(16))) unsigned short As[64 * 64];
  __shared__ __attribute__((aligned(16))) unsigned short Bs[128 * 64];
  const int tid = threadIdx.x;
  const int wave = tid >> 6, lane = tid & 63;
  const int quad = lane >> 4, ln = lane & 15;

  const int fp = (int)blockIdx.x + ((int)blockIdx.y << 3);
  const int xr = fp & 7, sl = fp >> 3;
  const int nx = sl & 7;                    // n-tile 0..7
  const int ny = xr * 16 + (sl >> 3);       // m-panel 0..127
  const int m0 = ny * 64, n0 = nx * 128;
  const int wm = (wave >> 1) * 32, wn = (wave & 1) * 64;

  f32x4 acc[2][4];
#pragma unroll
  for (int i = 0; i < 2; ++i)
#pragma unroll
    for (int j = 0; j < 4; ++j)
#pragma unroll
      for (int r = 0; r < 4; ++r) acc[i][j][r] = 0.f;

  for (int k0 = 0; k0 < K; k0 += 64) {
#pragma unroll
    for (int it = 0; it < 2; ++it) {
      const int idx = it * 256 + tid;
      const int row = idx >> 3, ch = idx & 7;
      const int gch = ch ^ (row & 7);
      __builtin_amdgcn_global_load_lds(
          (gas_t)(const void*)(A + (size_t)(m0 + row) * K + k0 + gch * 8),
          (las_t)(void*)((char*)As + idx * 16), 16, 0, 0);
    }
#pragma unroll
    for (int it = 0; it < 4; ++it) {
      const int idx = it * 256 + tid;
      const int row = idx >> 3, ch = idx & 7;
      const int gch = ch ^ (row & 7);
      __builtin_amdgcn_global_load_lds(
          (gas_t)(const void*)(Bm + (size_t)(n0 + row) * K + k0 + gch * 8),
          (las_t)(void*)((char*)Bs + idx * 16), 16, 0, 0);
    }
    __syncthreads();
#pragma unroll
    for (int kc = 0; kc < 2; ++kc) {
      bf16x8 af[2], bfr[4];
#pragma unroll
      for (int t = 0; t < 2; ++t) {
        const int ra = wm + t * 16 + ln;
        af[t] = *(const bf16x8*)(As + ra * 64 + ((kc * 4 + quad) ^ (ra & 7)) * 8);
      }
#pragma unroll
      for (int t = 0; t < 4; ++t) {
        const int rb = wn + t * 16 + ln;
        bfr[t] = *(const bf16x8*)(Bs + rb * 64 + ((kc * 4 + quad) ^ (rb & 7)) * 8);
      }
#pragma unroll
      for (int mt = 0; mt < 2; ++mt)
#pragma unroll
        for (int nt = 0; nt < 4; ++nt)
          acc[mt][nt] = mfma16(bfr[nt], af[mt], acc[mt][nt]);  // swapped
    }
    __syncthreads();
  }

#pragma unroll
  for (int mt = 0; mt < 2; ++mt) {
#pragma unroll
    for (int nt = 0; nt < 4; ++nt) {
      const int row  = m0 + wm + mt * 16 + ln;        // token
      const int colb = n0 + wn + nt * 16 + quad * 4;  // feature base
      const float4 bv = *(const float4*)(bias + colb);
      float4 ov;
      ov.x = acc[mt][nt][0] + bv.x; ov.y = acc[mt][nt][1] + bv.y;
      ov.z = acc[mt][nt][2] + bv.z; ov.w = acc[mt][nt][3] + bv.w;
      *(float4*)(Cf + (size_t)row * N + colb) = ov;
    }
  }
}

// ---------------- fused causal attention, V == Q (reference bug) -------------
// v9 (proven 76.2us): v5 body + XCD flat swizzle (FETCH 193MB -> 21MB).
// MfmaUtil 19% = exact MFMA floor; VALUBusy 54% is the dominant pipe. Frozen.
__global__ __launch_bounds__(256) void attn_kernel(
    const unsigned short* __restrict__ QT,  // [b,h][d=64][s=2048]
    const unsigned short* __restrict__ Kb,  // [b*s][E] row-major, pre-scaled
    unsigned short* __restrict__ Ab) {      // [b*s][E] row-major
  __shared__ __attribute__((aligned(16))) unsigned short Ks[64 * 64];
  __shared__ __attribute__((aligned(16))) unsigned short Vs[64 * 64];
  __shared__ __attribute__((aligned(16))) unsigned short Ps[4][16 * 72];

  const int tid = threadIdx.x;
  const int wave = tid >> 6, lane = tid & 63;
  const int quad = lane >> 4, ln = lane & 15;

  // XCD swizzle (assumes XCD = flat_id % 8): 16 q-chunk blocks of one (b,h)
  // contiguous on one XCD. Bijective over 1024 blocks.
  const int fp = (int)blockIdx.x + ((int)blockIdx.y << 4) + ((int)blockIdx.z << 8);
  const int xr = fp & 7, sl = fp >> 3;
  const int bx = sl & 15;                 // q-pair index 0..15
  const int g  = xr * 8 + (sl >> 4);      // (b,h) group 0..63
  const int h = g & 15, b = g >> 4;

  const size_t hoff  = ((size_t)b * PS) * PE + (size_t)h * PD;
  const size_t hofft = ((size_t)(b * PH + h) * PD) * PS;
  const int srow = tid >> 3, sch = tid & 7;

  for (int pass = 0; pass < 2; ++pass) {
    const int qc = pass ? bx : 31 - bx;
    const int qw0 = qc * 64 + wave * 16;

    // Q fragment: 16 q-rows x 64 d, B-operand layout (lane ln = q-row qw0+ln)
    bf16x8 qfr[2];
#pragma unroll
    for (int c = 0; c < 2; ++c) {
      union { unsigned short u[8]; bf16x8 v; } tmp;
#pragma unroll
      for (int j = 0; j < 8; ++j)
        tmp.u[j] = QT[hofft + (size_t)(c * 32 + quad * 8 + j) * PS + qw0 + ln];
      qfr[c] = tmp.v;
    }

    f32x4 o[4];
    float psum = 0.f;
#pragma unroll
    for (int td = 0; td < 4; ++td)
#pragma unroll
      for (int r = 0; r < 4; ++r) o[td][r] = 0.f;

    const int ktend = qc + 1;
    for (int kt = 0; kt < ktend; ++kt) {
      const int k0 = kt * 64;

#pragma unroll
      for (int r = 0; r < 2; ++r) {
        const int row = r * 32 + srow;
        const int gch = sch ^ (row & 7);
        __builtin_amdgcn_global_load_lds(
            (gas_t)(const void*)(Kb + hoff + (size_t)(k0 + row) * PE + gch * 8),
            (las_t)(void*)((char*)Ks + (r * 256 + tid) * 16), 16, 0, 0);
        __builtin_amdgcn_global_load_lds(
            (gas_t)(const void*)(QT + hofft + (size_t)row * PS + k0 + gch * 8),
            (las_t)(void*)((char*)Vs + (r * 256 + tid) * 16), 16, 0, 0);
      }
      __syncthreads();

      // QK^T: sacc[mk] covers k-rows (mk*16 + quad*4 + r), q-col = ln
      f32x4 sacc[4];
#pragma unroll
      for (int mk = 0; mk < 4; ++mk)
#pragma unroll
        for (int r = 0; r < 4; ++r) sacc[mk][r] = 0.f;
      __builtin_amdgcn_s_setprio(1);
#pragma unroll
      for (int c = 0; c < 2; ++c) {
        const int ch = ((c * 4 + quad) ^ (ln & 7)) * 8;
        bf16x8 kf[4];
#pragma unroll
        for (int mk = 0; mk < 4; ++mk)
          kf[mk] = *(const bf16x8*)(Ks + (mk * 16 + ln) * 64 + ch);
#pragma unroll
        for (int mk = 0; mk < 4; ++mk)
          sacc[mk] = mfma16(kf[mk], qfr[c], sacc[mk]);
      }
      __builtin_amdgcn_s_setprio(0);

      const bool edge = (k0 + 63) > qw0;
#pragma unroll
      for (int mk = 0; mk < 4; ++mk) {
        float p[4];
#pragma unroll
        for (int r = 0; r < 4; ++r)
          p[r] = __builtin_amdgcn_exp2f(sacc[mk][r]);
        if (edge) {
          const int qg = qw0 + ln;
#pragma unroll
          for (int r = 0; r < 4; ++r) {
            const int kg = k0 + mk * 16 + quad * 4 + r;
            p[r] = (kg <= qg) ? p[r] : 0.f;
          }
        }
        psum += (p[0] + p[1]) + (p[2] + p[3]);
        union { __hip_bfloat162 h2; unsigned int u; } u01, u23;
        u01.h2 = __float22bfloat162_rn(float2{p[0], p[1]});
        u23.h2 = __float22bfloat162_rn(float2{p[2], p[3]});
        *(uint2*)(&Ps[wave][ln * 72 + mk * 16 + quad * 4]) =
            uint2{u01.u, u23.u};
      }

      // PV: o[td] covers d-cols td*16+ln, q-rows quad*4+r
      __builtin_amdgcn_s_setprio(1);
#pragma unroll
      for (int c = 0; c < 2; ++c) {
        const int ch = ((c * 4 + quad) ^ (ln & 7)) * 8;
        bf16x8 pf = *(const bf16x8*)(&Ps[wave][ln * 72 + c * 32 + quad * 8]);
#pragma unroll
        for (int td = 0; td < 4; ++td) {
          bf16x8 vfd = *(const bf16x8*)(Vs + (td * 16 + ln) * 64 + ch);
          o[td] = mfma16(pf, vfd, o[td]);
        }
      }
      __builtin_amdgcn_s_setprio(0);
      __syncthreads();
    }

    psum += __shfl_xor(psum, 16, 64);
    psum += __shfl_xor(psum, 32, 64);
    float invq[4];
#pragma unroll
    for (int r = 0; r < 4; ++r)
      invq[r] = 1.f / __shfl(psum, quad * 4 + r, 64);

#pragma unroll
    for (int r = 0; r < 4; ++r) {
      const int qg = qw0 + quad * 4 + r;
#pragma unroll
      for (int td = 0; td < 4; ++td)
        Ab[hoff + (size_t)qg * PE + td * 16 + ln] =
            f2bf(o[td][r] * invq[r]);
    }
  }
}

// ---------------------------------------------------------------------------
extern "C" void kernel_launch(void* const* d_in, const int* in_sizes, int n_in,
                              void* d_out, int out_size, void* d_ws, size_t ws_size,
                              hipStream_t stream) {
  (void)in_sizes; (void)n_in; (void)out_size; (void)ws_size;
  const float* x  = (const float*)d_in[0];
  const float* Wk = (const float*)d_in[1];
  const float* Wq = (const float*)d_in[2];
  // d_in[3] = Wv : dead in the reference (V = Q bug) — never touched.
  const float* Wo = (const float*)d_in[4];
  const float* bo = (const float*)d_in[5];
  float* out = (float*)d_out;

  char* ws = (char*)d_ws;
  unsigned short* xb  = (unsigned short*)(ws);                       // 16 MiB
  unsigned short* wkb = (unsigned short*)(ws + (16u << 20));         //  2 MiB
  unsigned short* wqb = (unsigned short*)(ws + (18u << 20));         //  2 MiB
  unsigned short* wob = (unsigned short*)(ws + (20u << 20));         //  2 MiB
  unsigned short* QT  = (unsigned short*)(ws + (22u << 20));         // 16 MiB
  unsigned short* Kb  = (unsigned short*)(ws + (38u << 20));         // 16 MiB
  unsigned short* Ab  = xb;  // alias: xb dead after gemm_qknt

  const int M = PB * PS;  // 8192

  // 1) fp32 -> bf16
  cvt_kernel<<<dim3(CVT_BLOCKS), dim3(256), 0, stream>>>(
      x, Wk, Wq, Wo, xb, wkb, wqb, wob);

  // 2) Q = x Wq^T (-> QT transposed), K = x Wk^T (-> row-major, scaled).
  //    64x128 tiles, 2048 blocks, z-interleaved XCD panels.
  gemm_qknt<<<dim3(PE / 128, M / 64, 2), dim3(256), 0, stream>>>(
      xb, wqb, wkb, QT, Kb);

  // 3) causal attention (V = Q) — v9 frozen (76us)
  attn_kernel<<<dim3(16, PH, PB), dim3(256), 0, stream>>>(QT, Kb, Ab);

  // 4) out = attn Wo^T + bo (fp32) — 64x128 tiles (R10 version)
  gemm_out<<<dim3(PE / 128, M / 64), dim3(256), 0, stream>>>(
      Ab, wob, bo, out);
}

// Round 14
// 234.075 us; speedup vs baseline: 2.2435x; 1.0289x over previous
//
#include <hip/hip_runtime.h>
#include <hip/hip_bf16.h>

// Problem constants (B,S,E,H,D) = (4,2048,1024,16,64)
#define PB 4
#define PS 2048
#define PE 1024
#define PH 16
#define PD 64

typedef __attribute__((ext_vector_type(8))) short bf16x8;
typedef __attribute__((ext_vector_type(4))) float f32x4;
typedef const __attribute__((address_space(1))) unsigned int* gas_t;
typedef __attribute__((address_space(3))) unsigned int* las_t;

__device__ __forceinline__ unsigned short f2bf(float f) {
  union { float f; unsigned int u; } v;
  v.f = f;
  unsigned int u = v.u;
  u += 0x7fffu + ((u >> 16) & 1u);  // RNE
  return (unsigned short)(u >> 16);
}

__device__ __forceinline__ f32x4 mfma16(bf16x8 a, bf16x8 b, f32x4 c) {
  return __builtin_amdgcn_mfma_f32_16x16x32_bf16(a, b, c, 0, 0, 0);
}

// ---------------- fp32 -> bf16 conversion (x, Wk, Wq, Wo fused) --------------
#define CVT_GROUPS ((PB * PS * PE + 3 * PE * PE) / 4)
#define CVT_BLOCKS (CVT_GROUPS / 256)   // 11264
__global__ __launch_bounds__(256) void cvt_kernel(
    const float* __restrict__ x, const float* __restrict__ wk,
    const float* __restrict__ wq, const float* __restrict__ wo,
    unsigned short* __restrict__ xb, unsigned short* __restrict__ wkb,
    unsigned short* __restrict__ wqb, unsigned short* __restrict__ wob) {
  const long long NX = (long long)PB * PS * PE;   // 8388608
  const long long NW = (long long)PE * PE;        // 1048576
  long long i = ((long long)blockIdx.x * 256 + threadIdx.x) * 4;
  const float* src;
  unsigned short* dst;
  long long off;
  if (i < NX)               { src = x;  dst = xb;  off = i; }
  else if (i < NX + NW)     { src = wk; dst = wkb; off = i - NX; }
  else if (i < NX + 2 * NW) { src = wq; dst = wqb; off = i - NX - NW; }
  else                      { src = wo; dst = wob; off = i - NX - 2 * NW; }
  float4 v = *(const float4*)(src + off);
  ushort4 o;
  o.x = f2bf(v.x); o.y = f2bf(v.y); o.z = f2bf(v.z); o.w = f2bf(v.w);
  *(ushort4*)(dst + off) = o;
}

// ---------------- Q / K NT GEMM, 64x128 tiles, split by panel parity --------
// R12 structure; R13 change: within-XCD traversal is PANEL-UNIT fastest /
// n-tile SLOWEST. Concurrent blocks on one XCD now share ONE Bq + ONE Bk
// n-tile (0.5MB) + 16 A-panels (2MB) = ~2.5MB <= 4MB L2 (was 6MB with
// n-tile fastest -> staging missed L2, barrier drained HBM-class latency
// every K-step). A read from HBM once, L2-resident across all 8 nx phases.
__global__ __launch_bounds__(256) void gemm_qknt(
    const unsigned short* __restrict__ A, const unsigned short* __restrict__ Bq,
    const unsigned short* __restrict__ Bk,
    unsigned short* __restrict__ QT, unsigned short* __restrict__ Kb) {
  const int K = PE, N = PE;
  __shared__ __attribute__((aligned(16))) unsigned short As[64 * 64];
  __shared__ __attribute__((aligned(16))) unsigned short Bs[128 * 64];
  const int tid = threadIdx.x;
  const int wave = tid >> 6, lane = tid & 63;
  const int quad = lane >> 4, ln = lane & 15;

  // XCD swizzle (assumes XCD = flat_id % 8). Per XCD: 256 blocks =
  // 32 panel-units (fastest) x 8 n-tiles (slowest). Bijective over 2048.
  const int fp = (int)blockIdx.x + ((int)blockIdx.y << 3) + ((int)blockIdx.z << 10);
  const int xr = fp & 7, sl = fp >> 3;         // sl 0..255
  const int pu = sl & 31;                      // panel-unit within XCD
  const int nx = sl >> 5;                      // n-tile 0..7 (slowest)
  const int isK = pu & 1;
  const int ny = xr * 16 + (pu >> 1);          // m-panel 0..127
  const int m0 = ny * 64, n0 = nx * 128;
  const int wm = (wave >> 1) * 32, wn = (wave & 1) * 64;
  const unsigned short* __restrict__ Bsrc = isK ? Bk : Bq;

  f32x4 acc[2][4];
#pragma unroll
  for (int i = 0; i < 2; ++i)
#pragma unroll
    for (int j = 0; j < 4; ++j)
#pragma unroll
      for (int r = 0; r < 4; ++r) acc[i][j][r] = 0.f;

  for (int k0 = 0; k0 < K; k0 += 64) {
#pragma unroll
    for (int it = 0; it < 2; ++it) {
      const int idx = it * 256 + tid;
      const int row = idx >> 3, ch = idx & 7;
      const int gch = ch ^ (row & 7);
      __builtin_amdgcn_global_load_lds(
          (gas_t)(const void*)(A + (size_t)(m0 + row) * K + k0 + gch * 8),
          (las_t)(void*)((char*)As + idx * 16), 16, 0, 0);
    }
#pragma unroll
    for (int it = 0; it < 4; ++it) {
      const int idx = it * 256 + tid;
      const int row = idx >> 3, ch = idx & 7;
      const int gch = ch ^ (row & 7);
      __builtin_amdgcn_global_load_lds(
          (gas_t)(const void*)(Bsrc + (size_t)(n0 + row) * K + k0 + gch * 8),
          (las_t)(void*)((char*)Bs + idx * 16), 16, 0, 0);
    }
    __syncthreads();
#pragma unroll
    for (int kc = 0; kc < 2; ++kc) {
      bf16x8 af[2], bfr[4];
#pragma unroll
      for (int t = 0; t < 2; ++t) {
        const int ra = wm + t * 16 + ln;
        af[t] = *(const bf16x8*)(As + ra * 64 + ((kc * 4 + quad) ^ (ra & 7)) * 8);
      }
#pragma unroll
      for (int t = 0; t < 4; ++t) {
        const int rb = wn + t * 16 + ln;
        bfr[t] = *(const bf16x8*)(Bs + rb * 64 + ((kc * 4 + quad) ^ (rb & 7)) * 8);
      }
      if (!isK) {
#pragma unroll
        for (int mt = 0; mt < 2; ++mt)
#pragma unroll
          for (int nt = 0; nt < 4; ++nt)
            acc[mt][nt] = mfma16(af[mt], bfr[nt], acc[mt][nt]);
      } else {
#pragma unroll
        for (int mt = 0; mt < 2; ++mt)
#pragma unroll
          for (int nt = 0; nt < 4; ++nt)
            acc[mt][nt] = mfma16(bfr[nt], af[mt], acc[mt][nt]);  // swapped
      }
    }
    __syncthreads();
  }

  const float CEXP = 0.045084220f;  // log2(e)/32 folded into K
  if (!isK) {
    // Q: D[token=quad*4+r][feat=ln] -> transposed per-head ushort4 store
#pragma unroll
    for (int mt = 0; mt < 2; ++mt)
#pragma unroll
      for (int nt = 0; nt < 4; ++nt) {
        const int row = m0 + wm + mt * 16 + quad * 4;  // token (+r)
        const int col = n0 + wn + nt * 16 + ln;        // feature
        const int b = row >> 11, s = row & 2047;
        const int h = col >> 6, d = col & 63;
        ushort4 ov;
        ov.x = f2bf(acc[mt][nt][0]); ov.y = f2bf(acc[mt][nt][1]);
        ov.z = f2bf(acc[mt][nt][2]); ov.w = f2bf(acc[mt][nt][3]);
        *(ushort4*)(QT + (((size_t)(b * PH + h) * PD + d) * PS + s)) = ov;
      }
  } else {
    // K: D[feat=quad*4+r][token=ln] -> row-major ushort4 store, pre-scaled
#pragma unroll
    for (int mt = 0; mt < 2; ++mt)
#pragma unroll
      for (int nt = 0; nt < 4; ++nt) {
        const int krow = m0 + wm + mt * 16 + ln;        // token
        const int kcol = n0 + wn + nt * 16 + quad * 4;  // feature base
        ushort4 kv;
        kv.x = f2bf(acc[mt][nt][0] * CEXP); kv.y = f2bf(acc[mt][nt][1] * CEXP);
        kv.z = f2bf(acc[mt][nt][2] * CEXP); kv.w = f2bf(acc[mt][nt][3] * CEXP);
        *(ushort4*)(Kb + (size_t)krow * N + kcol) = kv;
      }
  }
}

// ---------------- out-projection NT GEMM: C = A * Wo^T + bo (fp32) ----------
// 64x128 tiles; R13: panel-fastest / n-tile-slowest XCD traversal (16
// A-panels 2MB + 1 B n-tile 0.25MB per XCD cohort = L2-fit).
__global__ __launch_bounds__(256) void gemm_out(
    const unsigned short* __restrict__ A, const unsigned short* __restrict__ Bm,
    const float* __restrict__ bias, float* __restrict__ Cf) {
  const int K = PE, N = PE;
  __shared__ __attribute__((aligned(16))) unsigned short As[64 * 64];
  __shared__ __attribute__((aligned(16))) unsigned short Bs[128 * 64];
  const int tid = threadIdx.x;
  const int wave = tid >> 6, lane = tid & 63;
  const int quad = lane >> 4, ln = lane & 15;

  const int fp = (int)blockIdx.x + ((int)blockIdx.y << 3);
  const int xr = fp & 7, sl = fp >> 3;      // sl 0..127
  const int pu = sl & 15;                   // m-panel within XCD (fastest)
  const int nx = sl >> 4;                   // n-tile 0..7 (slowest)
  const int ny = xr * 16 + pu;              // m-panel 0..127
  const int m0 = ny * 64, n0 = nx * 128;
  const int wm = (wave >> 1) * 32, wn = (wave & 1) * 64;

  f32x4 acc[2][4];
#pragma unroll
  for (int i = 0; i < 2; ++i)
#pragma unroll
    for (int j = 0; j < 4; ++j)
#pragma unroll
      for (int r = 0; r < 4; ++r) acc[i][j][r] = 0.f;

  for (int k0 = 0; k0 < K; k0 += 64) {
#pragma unroll
    for (int it = 0; it < 2; ++it) {
      const int idx = it * 256 + tid;
      const int row = idx >> 3, ch = idx & 7;
      const int gch = ch ^ (row & 7);
      __builtin_amdgcn_global_load_lds(
          (gas_t)(const void*)(A + (size_t)(m0 + row) * K + k0 + gch * 8),
          (las_t)(void*)((char*)As + idx * 16), 16, 0, 0);
    }
#pragma unroll
    for (int it = 0; it < 4; ++it) {
      const int idx = it * 256 + tid;
      const int row = idx >> 3, ch = idx & 7;
      const int gch = ch ^ (row & 7);
      __builtin_amdgcn_global_load_lds(
          (gas_t)(const void*)(Bm + (size_t)(n0 + row) * K + k0 + gch * 8),
          (las_t)(void*)((char*)Bs + idx * 16), 16, 0, 0);
    }
    __syncthreads();
#pragma unroll
    for (int kc = 0; kc < 2; ++kc) {
      bf16x8 af[2], bfr[4];
#pragma unroll
      for (int t = 0; t < 2; ++t) {
        const int ra = wm + t * 16 + ln;
        af[t] = *(const bf16x8*)(As + ra * 64 + ((kc * 4 + quad) ^ (ra & 7)) * 8);
      }
#pragma unroll
      for (int t = 0; t < 4; ++t) {
        const int rb = wn + t * 16 + ln;
        bfr[t] = *(const bf16x8*)(Bs + rb * 64 + ((kc * 4 + quad) ^ (rb & 7)) * 8);
      }
#pragma unroll
      for (int mt = 0; mt < 2; ++mt)
#pragma unroll
        for (int nt = 0; nt < 4; ++nt)
          acc[mt][nt] = mfma16(bfr[nt], af[mt], acc[mt][nt]);  // swapped
    }
    __syncthreads();
  }

#pragma unroll
  for (int mt = 0; mt < 2; ++mt) {
#pragma unroll
    for (int nt = 0; nt < 4; ++nt) {
      const int row  = m0 + wm + mt * 16 + ln;        // token
      const int colb = n0 + wn + nt * 16 + quad * 4;  // feature base
      const float4 bv = *(const float4*)(bias + colb);
      float4 ov;
      ov.x = acc[mt][nt][0] + bv.x; ov.y = acc[mt][nt][1] + bv.y;
      ov.z = acc[mt][nt][2] + bv.z; ov.w = acc[mt][nt][3] + bv.w;
      *(float4*)(Cf + (size_t)row * N + colb) = ov;
    }
  }
}

// ---------------- fused causal attention, V == Q (reference bug) -------------
// v9 (proven 75.5-76.2us): v5 body + XCD flat swizzle (FETCH 193MB -> 21MB).
// MfmaUtil 19% = exact MFMA floor; VALUBusy 54% is the dominant pipe. Frozen.
__global__ __launch_bounds__(256) void attn_kernel(
    const unsigned short* __restrict__ QT,  // [b,h][d=64][s=2048]
    const unsigned short* __restrict__ Kb,  // [b*s][E] row-major, pre-scaled
    unsigned short* __restrict__ Ab) {      // [b*s][E] row-major
  __shared__ __attribute__((aligned(16))) unsigned short Ks[64 * 64];
  __shared__ __attribute__((aligned(16))) unsigned short Vs[64 * 64];
  __shared__ __attribute__((aligned(16))) unsigned short Ps[4][16 * 72];

  const int tid = threadIdx.x;
  const int wave = tid >> 6, lane = tid & 63;
  const int quad = lane >> 4, ln = lane & 15;

  // XCD swizzle (assumes XCD = flat_id % 8): 16 q-chunk blocks of one (b,h)
  // contiguous on one XCD. Bijective over 1024 blocks.
  const int fp = (int)blockIdx.x + ((int)blockIdx.y << 4) + ((int)blockIdx.z << 8);
  const int xr = fp & 7, sl = fp >> 3;
  const int bx = sl & 15;                 // q-pair index 0..15
  const int g  = xr * 8 + (sl >> 4);      // (b,h) group 0..63
  const int h = g & 15, b = g >> 4;

  const size_t hoff  = ((size_t)b * PS) * PE + (size_t)h * PD;
  const size_t hofft = ((size_t)(b * PH + h) * PD) * PS;
  const int srow = tid >> 3, sch = tid & 7;

  for (int pass = 0; pass < 2; ++pass) {
    const int qc = pass ? bx : 31 - bx;
    const int qw0 = qc * 64 + wave * 16;

    // Q fragment: 16 q-rows x 64 d, B-operand layout (lane ln = q-row qw0+ln)
    bf16x8 qfr[2];
#pragma unroll
    for (int c = 0; c < 2; ++c) {
      union { unsigned short u[8]; bf16x8 v; } tmp;
#pragma unroll
      for (int j = 0; j < 8; ++j)
        tmp.u[j] = QT[hofft + (size_t)(c * 32 + quad * 8 + j) * PS + qw0 + ln];
      qfr[c] = tmp.v;
    }

    f32x4 o[4];
    float psum = 0.f;
#pragma unroll
    for (int td = 0; td < 4; ++td)
#pragma unroll
      for (int r = 0; r < 4; ++r) o[td][r] = 0.f;

    const int ktend = qc + 1;
    for (int kt = 0; kt < ktend; ++kt) {
      const int k0 = kt * 64;

#pragma unroll
      for (int r = 0; r < 2; ++r) {
        const int row = r * 32 + srow;
        const int gch = sch ^ (row & 7);
        __builtin_amdgcn_global_load_lds(
            (gas_t)(const void*)(Kb + hoff + (size_t)(k0 + row) * PE + gch * 8),
            (las_t)(void*)((char*)Ks + (r * 256 + tid) * 16), 16, 0, 0);
        __builtin_amdgcn_global_load_lds(
            (gas_t)(const void*)(QT + hofft + (size_t)row * PS + k0 + gch * 8),
            (las_t)(void*)((char*)Vs + (r * 256 + tid) * 16), 16, 0, 0);
      }
      __syncthreads();

      // QK^T: sacc[mk] covers k-rows (mk*16 + quad*4 + r), q-col = ln
      f32x4 sacc[4];
#pragma unroll
      for (int mk = 0; mk < 4; ++mk)
#pragma unroll
        for (int r = 0; r < 4; ++r) sacc[mk][r] = 0.f;
      __builtin_amdgcn_s_setprio(1);
#pragma unroll
      for (int c = 0; c < 2; ++c) {
        const int ch = ((c * 4 + quad) ^ (ln & 7)) * 8;
        bf16x8 kf[4];
#pragma unroll
        for (int mk = 0; mk < 4; ++mk)
          kf[mk] = *(const bf16x8*)(Ks + (mk * 16 + ln) * 64 + ch);
#pragma unroll
        for (int mk = 0; mk < 4; ++mk)
          sacc[mk] = mfma16(kf[mk], qfr[c], sacc[mk]);
      }
      __builtin_amdgcn_s_setprio(0);

      const bool edge = (k0 + 63) > qw0;
#pragma unroll
      for (int mk = 0; mk < 4; ++mk) {
        float p[4];
#pragma unroll
        for (int r = 0; r < 4; ++r)
          p[r] = __builtin_amdgcn_exp2f(sacc[mk][r]);
        if (edge) {
          const int qg = qw0 + ln;
#pragma unroll
          for (int r = 0; r < 4; ++r) {
            const int kg = k0 + mk * 16 + quad * 4 + r;
            p[r] = (kg <= qg) ? p[r] : 0.f;
          }
        }
        psum += (p[0] + p[1]) + (p[2] + p[3]);
        union { __hip_bfloat162 h2; unsigned int u; } u01, u23;
        u01.h2 = __float22bfloat162_rn(float2{p[0], p[1]});
        u23.h2 = __float22bfloat162_rn(float2{p[2], p[3]});
        *(uint2*)(&Ps[wave][ln * 72 + mk * 16 + quad * 4]) =
            uint2{u01.u, u23.u};
      }

      // PV: o[td] covers d-cols td*16+ln, q-rows quad*4+r
      __builtin_amdgcn_s_setprio(1);
#pragma unroll
      for (int c = 0; c < 2; ++c) {
        const int ch = ((c * 4 + quad) ^ (ln & 7)) * 8;
        bf16x8 pf = *(const bf16x8*)(&Ps[wave][ln * 72 + c * 32 + quad * 8]);
#pragma unroll
        for (int td = 0; td < 4; ++td) {
          bf16x8 vfd = *(const bf16x8*)(Vs + (td * 16 + ln) * 64 + ch);
          o[td] = mfma16(pf, vfd, o[td]);
        }
      }
      __builtin_amdgcn_s_setprio(0);
      __syncthreads();
    }

    psum += __shfl_xor(psum, 16, 64);
    psum += __shfl_xor(psum, 32, 64);
    float invq[4];
#pragma unroll
    for (int r = 0; r < 4; ++r)
      invq[r] = 1.f / __shfl(psum, quad * 4 + r, 64);

#pragma unroll
    for (int r = 0; r < 4; ++r) {
      const int qg = qw0 + quad * 4 + r;
#pragma unroll
      for (int td = 0; td < 4; ++td)
        Ab[hoff + (size_t)qg * PE + td * 16 + ln] =
            f2bf(o[td][r] * invq[r]);
    }
  }
}

// ---------------------------------------------------------------------------
extern "C" void kernel_launch(void* const* d_in, const int* in_sizes, int n_in,
                              void* d_out, int out_size, void* d_ws, size_t ws_size,
                              hipStream_t stream) {
  (void)in_sizes; (void)n_in; (void)out_size; (void)ws_size;
  const float* x  = (const float*)d_in[0];
  const float* Wk = (const float*)d_in[1];
  const float* Wq = (const float*)d_in[2];
  // d_in[3] = Wv : dead in the reference (V = Q bug) — never touched.
  const float* Wo = (const float*)d_in[4];
  const float* bo = (const float*)d_in[5];
  float* out = (float*)d_out;

  char* ws = (char*)d_ws;
  unsigned short* xb  = (unsigned short*)(ws);                       // 16 MiB
  unsigned short* wkb = (unsigned short*)(ws + (16u << 20));         //  2 MiB
  unsigned short* wqb = (unsigned short*)(ws + (18u << 20));         //  2 MiB
  unsigned short* wob = (unsigned short*)(ws + (20u << 20));         //  2 MiB
  unsigned short* QT  = (unsigned short*)(ws + (22u << 20));         // 16 MiB
  unsigned short* Kb  = (unsigned short*)(ws + (38u << 20));         // 16 MiB
  unsigned short* Ab  = xb;  // alias: xb dead after gemm_qknt

  const int M = PB * PS;  // 8192

  // 1) fp32 -> bf16
  cvt_kernel<<<dim3(CVT_BLOCKS), dim3(256), 0, stream>>>(
      x, Wk, Wq, Wo, xb, wkb, wqb, wob);

  // 2) Q = x Wq^T (-> QT transposed), K = x Wk^T (-> row-major, scaled).
  //    64x128 tiles, 2048 blocks, panel-fastest XCD traversal.
  gemm_qknt<<<dim3(PE / 128, M / 64, 2), dim3(256), 0, stream>>>(
      xb, wqb, wkb, QT, Kb);

  // 3) causal attention (V = Q) — v9 frozen (75.5us)
  attn_kernel<<<dim3(16, PH, PB), dim3(256), 0, stream>>>(QT, Kb, Ab);

  // 4) out = attn Wo^T + bo (fp32) — 64x128 tiles, panel-fastest traversal
  gemm_out<<<dim3(PE / 128, M / 64), dim3(256), 0, stream>>>(
      Ab, wob, bo, out);
}